// Round 9
// baseline (2059.725 us; speedup 1.0000x reference)
//
#include <hip/hip_runtime.h>
#include <math.h>

// corr: (B=8, HW=4096, H=64, W=64) fp32; out same shape.
// out[b,s,p] = corr[b,s,p] * g[sy-iy(p)] * g[sx-ix(p)], idx(p)=argmax_s corr[b,s,p].
//
// Persistent manually-cooperative kernel. 512 blocks x 512 thr = 2 blocks/CU
// (co-resident by construction; __launch_bounds__(512,4) caps VGPR at 128).
// Per 2-batch group g: A(g) linear-streams 16-row panels, merging per-pixel
// argmax via packed u64 atomicMax; grid barrier; B(g) re-reads the L3-hot
// panel (NT loads: hit-without-allocate) overlapped with A(g+1) on half the
// blocks. All global streams are contiguous 256KB per block per job.
constexpr int HWc  = 4096;
constexpr int GRP  = 2;
constexpr int NGRP = 4;
constexpr int ROWS = 16;               // rows per job (16*16KB = 256KB linear)
constexpr int NBLK = 512;              // 2 blocks/CU * 256 CUs
constexpr int NTHR = 512;

typedef float f32x4 __attribute__((ext_vector_type(4)));
typedef unsigned long long u64;

__device__ __forceinline__ unsigned monokey(float f) {
    unsigned u = __float_as_uint(f);
    return u ^ ((unsigned)(((int)u) >> 31) | 0x80000000u);
}

// Grid barrier: monotone counter (memset to 0 each call -> deterministic
// across graph replays). Release fence before arrive, acquire after spin.
__device__ __forceinline__ void gridbar(unsigned* cnt, unsigned target) {
    __threadfence();
    __syncthreads();
    if (threadIdx.x == 0) {
        __hip_atomic_fetch_add(cnt, 1u, __ATOMIC_ACQ_REL, __HIP_MEMORY_SCOPE_AGENT);
        while (__hip_atomic_load(cnt, __ATOMIC_ACQUIRE, __HIP_MEMORY_SCOPE_AGENT) < target)
            __builtin_amdgcn_s_sleep(32);
    }
    __syncthreads();
    __threadfence();
}

// A: argmax partial over a 16-row panel of batch b. Regular loads (allocate
// L3 for B's re-read). Packed key (monokey(max)<<32 | 4095-idx): atomicMax is
// order-independent; larger 4095-idx wins ties == first occurrence (jnp).
__device__ __forceinline__ void a_job(const float* __restrict__ corr,
                                      u64* __restrict__ fid, int b, int rr) {
    int s0 = rr * ROWS;
    int px = threadIdx.x * 8;
    const float* src = corr + (size_t)b * HWc * HWc + (size_t)s0 * HWc + px;

    float bm[8]; int bi[8];
    #pragma unroll
    for (int e = 0; e < 8; ++e) { bm[e] = -INFINITY; bi[e] = 0; }

    #pragma unroll
    for (int r = 0; r < ROWS; ++r) {
        float4 va = *reinterpret_cast<const float4*>(src + (size_t)r * HWc);
        float4 vb = *reinterpret_cast<const float4*>(src + (size_t)r * HWc + 4);
        int k = s0 + r;
        if (va.x > bm[0]) { bm[0] = va.x; bi[0] = k; }
        if (va.y > bm[1]) { bm[1] = va.y; bi[1] = k; }
        if (va.z > bm[2]) { bm[2] = va.z; bi[2] = k; }
        if (va.w > bm[3]) { bm[3] = va.w; bi[3] = k; }
        if (vb.x > bm[4]) { bm[4] = vb.x; bi[4] = k; }
        if (vb.y > bm[5]) { bm[5] = vb.y; bi[5] = k; }
        if (vb.z > bm[6]) { bm[6] = vb.z; bi[6] = k; }
        if (vb.w > bm[7]) { bm[7] = vb.w; bi[7] = k; }
    }
    u64* f = fid + ((size_t)b << 12) + px;
    #pragma unroll
    for (int e = 0; e < 8; ++e)
        atomicMax(&f[e], ((u64)monokey(bm[e]) << 32) | (unsigned)(4095 - bi[e]));
}

// B: apply pass over the same panel geometry. NT loads (hit L3, no re-alloc),
// NT stores (don't evict the next group's slab). sy constant per panel.
__device__ __forceinline__ void b_job(const float* __restrict__ corr,
                                      const u64* __restrict__ fid,
                                      float* __restrict__ out,
                                      const float* __restrict__ gtab,
                                      int b, int rr) {
    int s0 = rr * ROWS, sy = s0 >> 6, sxb = s0 & 63;
    int px = threadIdx.x * 8;
    const u64* f = fid + ((size_t)b << 12) + px;

    float gy[8]; int ic[8];
    #pragma unroll
    for (int e = 0; e < 8; ++e) {
        u64 key = __hip_atomic_load(&f[e], __ATOMIC_RELAXED, __HIP_MEMORY_SCOPE_AGENT);
        int idx = 4095 - (int)(unsigned)(key & 0xFFFFFFFFull);
        gy[e] = gtab[sy - (idx >> 6) + 63];
        ic[e] = sxb + 63 - (idx & 63);             // gx(r) = gtab[ic + r]
    }

    size_t base = (size_t)b * HWc * HWc + (size_t)s0 * HWc + px;
    const float* cs = corr + base;
    float*       os = out  + base;

    #pragma unroll
    for (int r = 0; r < ROWS; ++r) {
        f32x4 va = __builtin_nontemporal_load(reinterpret_cast<const f32x4*>(cs + (size_t)r * HWc));
        f32x4 vb = __builtin_nontemporal_load(reinterpret_cast<const f32x4*>(cs + (size_t)r * HWc + 4));
        f32x4 oa, ob;
        #pragma unroll
        for (int e = 0; e < 4; ++e) {
            oa[e] = va[e] * gy[e]     * gtab[ic[e] + r];
            ob[e] = vb[e] * gy[e + 4] * gtab[ic[e + 4] + r];
        }
        __builtin_nontemporal_store(oa, reinterpret_cast<f32x4*>(os + (size_t)r * HWc));
        __builtin_nontemporal_store(ob, reinterpret_cast<f32x4*>(os + (size_t)r * HWc + 4));
    }
}

__global__ __launch_bounds__(NTHR, 4) void k_persist(
        const float* __restrict__ corr, float* __restrict__ out,
        u64* __restrict__ fid, unsigned* __restrict__ cnt) {
    __shared__ float gtab[128];                    // g[d+63], d in [-63,63]
    if (threadIdx.x < 128) {
        float d = (float)((int)threadIdx.x - 63);
        gtab[threadIdx.x] = __expf(-d * d * (1.0f / 50.0f));   // 2*sigma^2 = 50
    }
    __syncthreads();

    int bid = blockIdx.x;
    int bl  = bid & 1;                             // batch within group
    int rr  = bid >> 1;                            // 16-row panel index [0,256)

    // Pipeline: A0 | bar | B0||A1 | bar | B1||A2 | bar | B2||A3 | bar | B3
    a_job(corr, fid, bl, rr);
    gridbar(cnt, NBLK);

    for (int g = 0; g < NGRP; ++g) {
        if (g + 1 < NGRP) {
            if (bl == 0) {
                b_job(corr, fid, out, gtab, g * GRP + bl, rr);
                a_job(corr, fid, (g + 1) * GRP + bl, rr);
            } else {
                a_job(corr, fid, (g + 1) * GRP + bl, rr);
                b_job(corr, fid, out, gtab, g * GRP + bl, rr);
            }
            gridbar(cnt, (unsigned)((g + 2) * NBLK));
        } else {
            b_job(corr, fid, out, gtab, g * GRP + bl, rr);
        }
    }
}

extern "C" void kernel_launch(void* const* d_in, const int* in_sizes, int n_in,
                              void* d_out, int out_size, void* d_ws, size_t ws_size,
                              hipStream_t stream) {
    const float* corr = (const float*)d_in[0];
    float* out = (float*)d_out;

    // ws: fid (8*4096 u64 = 256 KB) + barrier counter. Zeroed every call
    // (graph-replayed) -> deterministic, poison-safe.
    size_t fid_bytes = (size_t)8 * HWc * sizeof(u64);
    u64* fid = (u64*)d_ws;
    unsigned* cnt = (unsigned*)((char*)d_ws + fid_bytes);
    hipMemsetAsync(d_ws, 0, fid_bytes + 256, stream);

    k_persist<<<NBLK, NTHR, 0, stream>>>(corr, out, fid, cnt);
}

// Round 10
// 298.260 us; speedup vs baseline: 6.9058x; 6.9058x over previous
//
#include <hip/hip_runtime.h>
#include <math.h>

// corr: (B=8, HW=4096, H=64, W=64) fp32; out same shape.
// out[b,s,p] = corr[b,s,p] * g[sy-iy(p)] * g[sx-ix(p)], idx(p)=argmax_s corr[b,s,p].
//
// Per 2-batch group (128MB slab, L3-resident):
//   k1: row-linear split-K argmax -> per-panel packed u64 partials (NO atomics)
//   k2: coalesced 128-way reduce of partials -> fidx
//   k3: row-linear apply; NT loads hit L3 (proven R9: FETCH=0.56GB), NT stores.
constexpr int Bc   = 8;
constexpr int HWc  = 4096;
constexpr int GRP  = 2;
constexpr int ROWS = 32;                   // rows per panel (512KB contiguous)
constexpr int PAN  = HWc / ROWS;           // 128 panels per batch
constexpr int NTHR = 512;

typedef float f32x4 __attribute__((ext_vector_type(4)));
typedef unsigned long long u64;

__device__ __forceinline__ unsigned monokey(float f) {
    unsigned u = __float_as_uint(f);
    return u ^ ((unsigned)(((int)u) >> 31) | 0x80000000u);
}
__device__ __forceinline__ u64 packkey(float m, int idx) {
    // larger value wins; equal value -> larger (4095-idx) wins == smaller idx
    // == first occurrence (matches jnp.argmax). Normal data, no NaN.
    return ((u64)monokey(m) << 32) | (unsigned)(4095 - idx);
}

// ---------------------------------------------------------------------------
// k1: argmax partial over one 32-row panel. grid = GRP*PAN = 256 blocks.
// Block reads 512KB contiguous (rows s0..s0+31). Thread owns px tid*4 (+2048):
// every wave-instruction touches a contiguous 1KB segment. Partials go to
// disjoint addresses -> zero contention, pure streaming.
// ---------------------------------------------------------------------------
__global__ __launch_bounds__(NTHR) void k_argmax(
        const float* __restrict__ corr, int b0, u64* __restrict__ pp) {
    int bl = blockIdx.x & 1;
    int rr = blockIdx.x >> 1;                 // 0..127
    int b  = b0 + bl;
    int s0 = rr * ROWS;
    int plo = threadIdx.x * 4, phi = 2048 + plo;

    const float* src = corr + (size_t)b * HWc * HWc + (size_t)s0 * HWc;

    float bmA[4], bmB[4]; int biA[4], biB[4];
    #pragma unroll
    for (int e = 0; e < 4; ++e) {
        bmA[e] = -INFINITY; bmB[e] = -INFINITY; biA[e] = 0; biB[e] = 0;
    }

    #pragma unroll 4
    for (int r = 0; r < ROWS; ++r) {
        f32x4 va = *reinterpret_cast<const f32x4*>(src + (size_t)r * HWc + plo);
        f32x4 vb = *reinterpret_cast<const f32x4*>(src + (size_t)r * HWc + phi);
        int k = s0 + r;
        #pragma unroll
        for (int e = 0; e < 4; ++e) {
            if (va[e] > bmA[e]) { bmA[e] = va[e]; biA[e] = k; }
            if (vb[e] > bmB[e]) { bmB[e] = vb[e]; biB[e] = k; }
        }
    }

    u64* dst = pp + (((size_t)(bl * PAN + rr)) << 12);
    #pragma unroll
    for (int e = 0; e < 4; ++e) {
        dst[plo + e] = packkey(bmA[e], biA[e]);
        dst[phi + e] = packkey(bmB[e], biB[e]);
    }
}

// ---------------------------------------------------------------------------
// k2: reduce PAN partials -> final key per (batch,pixel). grid = 16 blocks.
// Loads are coalesced across threads (consecutive px); 128 independent loads
// per thread, unroll 8. Partials are L2/L3-resident (just written).
// ---------------------------------------------------------------------------
__global__ __launch_bounds__(NTHR) void k_reduce(
        const u64* __restrict__ pp, u64* __restrict__ fidx) {
    int g  = blockIdx.x * NTHR + threadIdx.x;   // 0 .. GRP*HWc-1
    int bl = g >> 12;
    int px = g & 4095;

    u64 best = 0;                               // below any real key
    #pragma unroll 8
    for (int rr = 0; rr < PAN; ++rr) {
        u64 v = pp[(((size_t)(bl * PAN + rr)) << 12) + px];
        best = v > best ? v : best;
    }
    fidx[g] = best;
}

// ---------------------------------------------------------------------------
// k3: apply pass, same panel geometry as k1. sy = s0>>6 constant per panel
// (32 | 64). NT loads: hit L3 without re-allocating (R9-verified). Separable
// Gaussian: gy per pixel in regs, gx = gtab[ic + r] one LDS read per element.
// NT stores keep the output stream from evicting the next group's slab.
// ---------------------------------------------------------------------------
__global__ __launch_bounds__(NTHR) void k_apply(
        const float* __restrict__ corr, int b0,
        const u64* __restrict__ fidx, float* __restrict__ out) {
    int bl = blockIdx.x & 1;
    int rr = blockIdx.x >> 1;
    int b  = b0 + bl;
    int s0 = rr * ROWS;
    int sy = s0 >> 6, sxb = s0 & 63;
    int plo = threadIdx.x * 4, phi = 2048 + plo;

    __shared__ float gtab[128];                 // g[d+63], d in [-63,63]
    if (threadIdx.x < 128) {
        float d = (float)((int)threadIdx.x - 63);
        gtab[threadIdx.x] = __expf(-d * d * (1.0f / 50.0f));   // 2*sigma^2 = 50
    }
    __syncthreads();

    const u64* f = fidx + ((size_t)bl << 12);
    float gyA[4], gyB[4]; int icA[4], icB[4];
    #pragma unroll
    for (int e = 0; e < 4; ++e) {
        int ia = 4095 - (int)(unsigned)(f[plo + e] & 0xFFFFFFFFull);
        int ib = 4095 - (int)(unsigned)(f[phi + e] & 0xFFFFFFFFull);
        gyA[e] = gtab[sy - (ia >> 6) + 63];
        gyB[e] = gtab[sy - (ib >> 6) + 63];
        icA[e] = sxb + 63 - (ia & 63);          // gx(r) = gtab[ic + r]
        icB[e] = sxb + 63 - (ib & 63);
    }

    size_t base = (size_t)b * HWc * HWc + (size_t)s0 * HWc;
    const float* cs = corr + base;
    float*       os = out  + base;

    #pragma unroll 4
    for (int r = 0; r < ROWS; ++r) {
        f32x4 va = __builtin_nontemporal_load(
            reinterpret_cast<const f32x4*>(cs + (size_t)r * HWc + plo));
        f32x4 vb = __builtin_nontemporal_load(
            reinterpret_cast<const f32x4*>(cs + (size_t)r * HWc + phi));
        f32x4 oa, ob;
        #pragma unroll
        for (int e = 0; e < 4; ++e) {
            oa[e] = va[e] * gyA[e] * gtab[icA[e] + r];
            ob[e] = vb[e] * gyB[e] * gtab[icB[e] + r];
        }
        __builtin_nontemporal_store(oa, reinterpret_cast<f32x4*>(os + (size_t)r * HWc + plo));
        __builtin_nontemporal_store(ob, reinterpret_cast<f32x4*>(os + (size_t)r * HWc + phi));
    }
}

extern "C" void kernel_launch(void* const* d_in, const int* in_sizes, int n_in,
                              void* d_out, int out_size, void* d_ws, size_t ws_size,
                              hipStream_t stream) {
    const float* corr = (const float*)d_in[0];
    float* out = (float*)d_out;

    // ws: pp (GRP*PAN*4096 u64 = 8 MB) + fidx (GRP*4096 u64 = 64 KB).
    // Both fully rewritten before each read -> no init, poison-safe,
    // deterministic across graph replays.
    u64* pp   = (u64*)d_ws;
    u64* fidx = pp + (size_t)GRP * PAN * HWc;

    for (int g = 0; g < Bc / GRP; ++g) {
        int b0 = g * GRP;
        k_argmax<<<GRP * PAN, NTHR, 0, stream>>>(corr, b0, pp);
        k_reduce<<<GRP * HWc / NTHR, NTHR, 0, stream>>>(pp, fidx);
        k_apply <<<GRP * PAN, NTHR, 0, stream>>>(corr, b0, fidx, out);
    }
}